// Round 1
// baseline (1079.136 us; speedup 1.0000x reference)
//
#include <hip/hip_runtime.h>

#define B_ 16
#define C_ 64
#define N_ 307
#define T_ 288
#define R_ 10

// ---------------------------------------------------------------------------
// Kernel 1: K[b,t,n] = sum_i alpha[i] * x[b,i,n,t]
// One thread per (b,n,t); loop over C=64 channels (stride N*T). Coalesced in t.
// ---------------------------------------------------------------------------
__global__ __launch_bounds__(256) void k_reduce(const float* __restrict__ x,
                                                const float* __restrict__ alpha,
                                                float* __restrict__ K) {
    __shared__ float a_s[C_];
    if (threadIdx.x < C_) a_s[threadIdx.x] = alpha[threadIdx.x];
    __syncthreads();
    int idx = blockIdx.x * blockDim.x + threadIdx.x;
    const int total = B_ * N_ * T_;
    if (idx >= total) return;
    int t = idx % T_;
    int n = (idx / T_) % N_;
    int b = idx / (N_ * T_);
    const float* xp = x + ((size_t)(b * C_) * N_ + n) * T_ + t;
    float s = 0.f;
#pragma unroll
    for (int i = 0; i < C_; ++i) s += a_s[i] * xp[(size_t)i * N_ * T_];
    K[((size_t)b * T_ + t) * N_ + n] = s;
}

// ---------------------------------------------------------------------------
// Kernel 2: KW1[b,t,r] = sum_n K[b,t,n]*W1[r,n];  QW2 likewise with W2.
// One thread per (b,t,matrix,r). K is L2-resident (5.7 MB).
// ---------------------------------------------------------------------------
__global__ __launch_bounds__(256) void k_proj(const float* __restrict__ K,
                                              const float* __restrict__ W1,
                                              const float* __restrict__ W2,
                                              float* __restrict__ KW1,
                                              float* __restrict__ QW2) {
    int idx = blockIdx.x * blockDim.x + threadIdx.x;
    const int total = B_ * T_ * 2 * R_;
    if (idx >= total) return;
    int r = idx % R_;
    int m = (idx / R_) % 2;
    int bt = idx / (2 * R_);
    const float* W = (m ? W2 : W1) + r * N_;
    const float* Kp = K + (size_t)bt * N_;
    float s = 0.f;
    for (int n = 0; n < N_; ++n) s += Kp[n] * W[n];
    (m ? QW2 : KW1)[bt * R_ + r] = s;
}

// ---------------------------------------------------------------------------
// Kernel 3: scores[b,t,s] = sum_r KW1[b,t,r]*QW2[b,s,r]; softmax over s.
// One wave (64 lanes) per (b,t); each lane owns up to 5 s-values.
// Writes A[b,t,s] coalesced (s contiguous).
// ---------------------------------------------------------------------------
__global__ __launch_bounds__(64) void k_softmax(const float* __restrict__ KW1,
                                                const float* __restrict__ QW2,
                                                float* __restrict__ A) {
    int bt = blockIdx.x;  // b*T_ + t
    int b = bt / T_;
    int lane = threadIdx.x;
    float kw[R_];
#pragma unroll
    for (int r = 0; r < R_; ++r) kw[r] = KW1[bt * R_ + r];
    float sc[5];
    float mx = -1e30f;
#pragma unroll
    for (int j = 0; j < 5; ++j) {
        int s = lane + j * 64;
        float v = -1e30f;
        if (s < T_) {
            const float* q = QW2 + ((size_t)b * T_ + s) * R_;
            v = 0.f;
#pragma unroll
            for (int r = 0; r < R_; ++r) v += kw[r] * q[r];
        }
        sc[j] = v;
        mx = fmaxf(mx, v);
    }
#pragma unroll
    for (int off = 32; off > 0; off >>= 1) mx = fmaxf(mx, __shfl_xor(mx, off));
    float sum = 0.f;
#pragma unroll
    for (int j = 0; j < 5; ++j) {
        int s = lane + j * 64;
        float e = (s < T_) ? __expf(sc[j] - mx) : 0.f;
        sc[j] = e;
        sum += e;
    }
#pragma unroll
    for (int off = 32; off > 0; off >>= 1) sum += __shfl_xor(sum, off);
    float inv = 1.f / sum;
#pragma unroll
    for (int j = 0; j < 5; ++j) {
        int s = lane + j * 64;
        if (s < T_) A[(size_t)bt * T_ + s] = sc[j] * inv;
    }
}

// ---------------------------------------------------------------------------
// Kernel 4: out[b,m,t] = sum_s X[b,m,s] * A[b,t,s]   (m = c*N+n, M = 19648)
// f32 tiled GEMM (NT form: both operands row-major, K=s innermost).
// BM=64 x BN=64 x BK=32, 256 threads, 4x4 register micro-tile.
// LDS tiles stored transposed [k][m] so micro-kernel uses ds_read_b128.
// M = 19648 = 307*64 exactly -> no m bounds. t bounded at 288.
// ---------------------------------------------------------------------------
#define BM 64
#define BN 64
#define BK 32

__global__ __launch_bounds__(256) void k_out(const float* __restrict__ x,
                                             const float* __restrict__ A,
                                             float* __restrict__ out) {
    int m0 = blockIdx.x * BM;
    int t0 = blockIdx.y * BN;
    int b = blockIdx.z;
    const float* Xb = x + (size_t)b * C_ * N_ * T_;
    const float* Ab = A + (size_t)b * T_ * T_;
    float* Ob = out + (size_t)b * C_ * N_ * T_;

    __shared__ __align__(16) float Xs[BK][BM + 4];  // [k][m], stride 68 floats (16B-aligned rows)
    __shared__ __align__(16) float As[BK][BN + 4];  // [k][t]

    int tid = threadIdx.x;
    int tx = tid & 15;   // t direction
    int ty = tid >> 4;   // m direction
    float acc[4][4] = {{0.f}};

    for (int s0 = 0; s0 < T_; s0 += BK) {
#pragma unroll
        for (int i = 0; i < 8; ++i) {
            int e = tid + i * 256;     // 0..2047
            int row = e >> 5;          // 0..63
            int col = e & 31;          // 0..31 (s within tile)
            Xs[col][row] = Xb[(size_t)(m0 + row) * T_ + (s0 + col)];
            int tr = t0 + row;
            As[col][row] = (tr < T_) ? Ab[(size_t)tr * T_ + (s0 + col)] : 0.f;
        }
        __syncthreads();
#pragma unroll
        for (int k = 0; k < BK; ++k) {
            const float4 av = *(const float4*)(&Xs[k][ty * 4]);
            const float4 bv = *(const float4*)(&As[k][tx * 4]);
            float a_[4] = {av.x, av.y, av.z, av.w};
            float b_[4] = {bv.x, bv.y, bv.z, bv.w};
#pragma unroll
            for (int i = 0; i < 4; ++i)
#pragma unroll
                for (int j = 0; j < 4; ++j) acc[i][j] = fmaf(a_[i], b_[j], acc[i][j]);
        }
        __syncthreads();
    }

#pragma unroll
    for (int i = 0; i < 4; ++i) {
        int m = m0 + ty * 4 + i;
#pragma unroll
        for (int j = 0; j < 4; ++j) {
            int t = t0 + tx * 4 + j;
            if (t < T_) Ob[(size_t)m * T_ + t] = acc[i][j];
        }
    }
}

// ---------------------------------------------------------------------------
extern "C" void kernel_launch(void* const* d_in, const int* in_sizes, int n_in,
                              void* d_out, int out_size, void* d_ws, size_t ws_size,
                              hipStream_t stream) {
    const float* x = (const float*)d_in[0];
    const float* W1 = (const float*)d_in[1];
    const float* W2 = (const float*)d_in[2];
    const float* alpha = (const float*)d_in[3];
    float* out = (float*)d_out;

    // workspace layout (floats): K [B*T*N] | KW1 [B*T*R] | QW2 [B*T*R] | A [B*T*T]
    float* K = (float*)d_ws;
    float* KW1 = K + (size_t)B_ * T_ * N_;              // 1,414,656
    float* QW2 = KW1 + (size_t)B_ * T_ * R_;            // +46,080
    float* A = QW2 + (size_t)B_ * T_ * R_;              // +46,080 (total ~11.3 MB)

    {
        int total = B_ * N_ * T_;
        k_reduce<<<(total + 255) / 256, 256, 0, stream>>>(x, alpha, K);
    }
    {
        int total = B_ * T_ * 2 * R_;
        k_proj<<<(total + 255) / 256, 256, 0, stream>>>(K, W1, W2, KW1, QW2);
    }
    k_softmax<<<B_ * T_, 64, 0, stream>>>(KW1, QW2, A);
    {
        dim3 grid(C_ * N_ / BM, (T_ + BN - 1) / BN, B_);  // 307 x 5 x 16
        k_out<<<grid, 256, 0, stream>>>(x, A, out);
    }
}

// Round 2
// 382.033 us; speedup vs baseline: 2.8247x; 2.8247x over previous
//
#include <hip/hip_runtime.h>

#define B_ 16
#define C_ 64
#define N_ 307
#define T_ 288
#define R_ 10
#define M_ (C_ * N_)  // 19648 = 307*64

typedef __attribute__((ext_vector_type(8))) short bf16x8;
typedef __attribute__((ext_vector_type(4))) float f32x4;

__device__ __forceinline__ unsigned short f2bf(float f) {
    unsigned int u = __float_as_uint(f);
    unsigned int r = (u + 0x7fffu + ((u >> 16) & 1u)) >> 16;  // RNE
    return (unsigned short)r;
}

// ---------------------------------------------------------------------------
// Kernel 1: K[b,t,n] = sum_i alpha[i]*x[b,i,n,t]; optionally also writes
// xbf = bf16(x) (same layout as x) so the big GEMM reads half the bytes.
// One thread per (b,n,t4): float4 over t, loop C=64 channels.
// ---------------------------------------------------------------------------
template <int WRITE_BF>
__global__ __launch_bounds__(256) void k_reduce(const float* __restrict__ x,
                                                const float* __restrict__ alpha,
                                                float* __restrict__ K,
                                                unsigned short* __restrict__ xbf) {
    __shared__ float a_s[C_];
    if (threadIdx.x < C_) a_s[threadIdx.x] = alpha[threadIdx.x];
    __syncthreads();
    const int T4 = T_ / 4;  // 72
    int idx = blockIdx.x * blockDim.x + threadIdx.x;
    const int total = B_ * N_ * T4;
    if (idx >= total) return;
    int t4 = idx % T4;
    int n = (idx / T4) % N_;
    int b = idx / (N_ * T4);
    const size_t chs = (size_t)N_ * T_;  // channel stride
    size_t base = ((size_t)(b * C_) * N_ + n) * T_ + t4 * 4;
    float4 s = {0.f, 0.f, 0.f, 0.f};
#pragma unroll 4
    for (int i = 0; i < C_; ++i) {
        float4 v = *(const float4*)(x + base + (size_t)i * chs);
        float a = a_s[i];
        s.x += a * v.x; s.y += a * v.y; s.z += a * v.z; s.w += a * v.w;
        if (WRITE_BF) {
            ushort4 w;
            w.x = f2bf(v.x); w.y = f2bf(v.y); w.z = f2bf(v.z); w.w = f2bf(v.w);
            *(ushort4*)(xbf + base + (size_t)i * chs) = w;
        }
    }
    int t = t4 * 4;
    size_t kb = ((size_t)b * T_ + t) * N_ + n;
    K[kb] = s.x; K[kb + N_] = s.y; K[kb + 2 * N_] = s.z; K[kb + 3 * N_] = s.w;
}

// ---------------------------------------------------------------------------
// Kernel 2: KW1[b,t,r] = sum_n K[b,t,n]*W1[r,n]; QW2 likewise. Tiny.
// ---------------------------------------------------------------------------
__global__ __launch_bounds__(256) void k_proj(const float* __restrict__ K,
                                              const float* __restrict__ W1,
                                              const float* __restrict__ W2,
                                              float* __restrict__ KW1,
                                              float* __restrict__ QW2) {
    int idx = blockIdx.x * blockDim.x + threadIdx.x;
    const int total = B_ * T_ * 2 * R_;
    if (idx >= total) return;
    int r = idx % R_;
    int m = (idx / R_) % 2;
    int bt = idx / (2 * R_);
    const float* W = (m ? W2 : W1) + r * N_;
    const float* Kp = K + (size_t)bt * N_;
    float s = 0.f;
    for (int n = 0; n < N_; ++n) s += Kp[n] * W[n];
    (m ? QW2 : KW1)[bt * R_ + r] = s;
}

// ---------------------------------------------------------------------------
// Kernel 3: scores -> softmax -> A (bf16). One wave per (b,t).
// ---------------------------------------------------------------------------
__global__ __launch_bounds__(64) void k_softmax(const float* __restrict__ KW1,
                                                const float* __restrict__ QW2,
                                                unsigned short* __restrict__ A) {
    int bt = blockIdx.x;
    int b = bt / T_;
    int lane = threadIdx.x;
    float kw[R_];
#pragma unroll
    for (int r = 0; r < R_; ++r) kw[r] = KW1[bt * R_ + r];
    float sc[5];
    float mx = -1e30f;
#pragma unroll
    for (int j = 0; j < 5; ++j) {
        int s = lane + j * 64;
        float v = -1e30f;
        if (s < T_) {
            const float* q = QW2 + ((size_t)b * T_ + s) * R_;
            v = 0.f;
#pragma unroll
            for (int r = 0; r < R_; ++r) v += kw[r] * q[r];
        }
        sc[j] = v;
        mx = fmaxf(mx, v);
    }
#pragma unroll
    for (int off = 32; off > 0; off >>= 1) mx = fmaxf(mx, __shfl_xor(mx, off));
    float sum = 0.f;
#pragma unroll
    for (int j = 0; j < 5; ++j) {
        int s = lane + j * 64;
        float e = (s < T_) ? __expf(sc[j] - mx) : 0.f;
        sc[j] = e;
        sum += e;
    }
#pragma unroll
    for (int off = 32; off > 0; off >>= 1) sum += __shfl_xor(sum, off);
    float inv = 1.f / sum;
#pragma unroll
    for (int j = 0; j < 5; ++j) {
        int s = lane + j * 64;
        if (s < T_) A[(size_t)bt * T_ + s] = f2bf(sc[j] * inv);
    }
}

// ---------------------------------------------------------------------------
// Kernel 4: out[b,m,t] = sum_s X[b,m,s]*A[b,t,s] via mfma_f32_16x16x32_bf16.
// BM=64 (exact: M=307*64), BN=96 (exact: T=3*96), BK=32, 256 thr = 4 waves 2x2.
// Wave tile 32x48 = 2x3 fragments. LDS rows padded to 40 bf16 (16B-aligned,
// <=2-way bank aliasing on ds_read_b128).
// Fragment maps (m89-verified): A: row=l&15, k=(l>>4)*8+e ; B: col=l&15,
// k=(l>>4)*8+e ; D: col=l&15, row=(l>>4)*4+r.
// ---------------------------------------------------------------------------
template <int XBF>
__global__ __launch_bounds__(256) void k_out(const float* __restrict__ xf,
                                             const unsigned short* __restrict__ xb,
                                             const unsigned short* __restrict__ A,
                                             float* __restrict__ out) {
    const int m0 = blockIdx.x * 64;
    const int t0 = blockIdx.y * 96;
    const int b = blockIdx.z;

    __shared__ __align__(16) unsigned short Xs[64][40];  // [m][s], pad to 40
    __shared__ __align__(16) unsigned short As[96][40];  // [t][s], pad to 40

    const int tid = threadIdx.x;
    const int lane = tid & 63;
    const int wid = tid >> 6;  // 0..3
    const int wm = wid & 1;    // m half (32 rows)
    const int wt = wid >> 1;   // t half (48 cols)
    const int c = lane & 15;
    const int kq = lane >> 4;  // k-quarter

    // staging assignments
    const int xr = tid >> 2, xq = tid & 3;  // X row 0..63, 8-elem chunk
    const int ar = tid >> 1, ah = tid & 1;  // A row 0..95 (tid<192), 16-elem half
    const size_t Xrow = (size_t)b * M_ * T_ + (size_t)(m0 + xr) * T_;
    const size_t Arow = ((size_t)b * T_ + (t0 + ar)) * T_;

    f32x4 acc[2][3];
#pragma unroll
    for (int i = 0; i < 2; ++i)
#pragma unroll
        for (int j = 0; j < 3; ++j) acc[i][j] = (f32x4){0.f, 0.f, 0.f, 0.f};

    for (int s0 = 0; s0 < T_; s0 += 32) {
        if (XBF) {
            uint4 v = *(const uint4*)(xb + Xrow + s0 + xq * 8);
            *(uint4*)&Xs[xr][xq * 8] = v;
        } else {
            float4 v0 = *(const float4*)(xf + Xrow + s0 + xq * 8);
            float4 v1 = *(const float4*)(xf + Xrow + s0 + xq * 8 + 4);
            ushort4 w0, w1;
            w0.x = f2bf(v0.x); w0.y = f2bf(v0.y); w0.z = f2bf(v0.z); w0.w = f2bf(v0.w);
            w1.x = f2bf(v1.x); w1.y = f2bf(v1.y); w1.z = f2bf(v1.z); w1.w = f2bf(v1.w);
            *(ushort4*)&Xs[xr][xq * 8] = w0;
            *(ushort4*)&Xs[xr][xq * 8 + 4] = w1;
        }
        if (tid < 192) {
            uint4 v0 = *(const uint4*)(A + Arow + s0 + ah * 16);
            uint4 v1 = *(const uint4*)(A + Arow + s0 + ah * 16 + 8);
            *(uint4*)&As[ar][ah * 16] = v0;
            *(uint4*)&As[ar][ah * 16 + 8] = v1;
        }
        __syncthreads();

        bf16x8 af[2], bfr[3];
#pragma unroll
        for (int i = 0; i < 2; ++i)
            af[i] = *(const bf16x8*)&Xs[wm * 32 + i * 16 + c][kq * 8];
#pragma unroll
        for (int j = 0; j < 3; ++j)
            bfr[j] = *(const bf16x8*)&As[wt * 48 + j * 16 + c][kq * 8];
#pragma unroll
        for (int i = 0; i < 2; ++i)
#pragma unroll
            for (int j = 0; j < 3; ++j)
                acc[i][j] = __builtin_amdgcn_mfma_f32_16x16x32_bf16(af[i], bfr[j], acc[i][j], 0, 0, 0);
        __syncthreads();
    }

    float* Ob = out + (size_t)b * M_ * T_;
#pragma unroll
    for (int i = 0; i < 2; ++i) {
#pragma unroll
        for (int j = 0; j < 3; ++j) {
            int t = t0 + wt * 48 + j * 16 + c;
#pragma unroll
            for (int r = 0; r < 4; ++r) {
                int m = m0 + wm * 32 + i * 16 + kq * 4 + r;
                Ob[(size_t)m * T_ + t] = acc[i][j][r];
            }
        }
    }
}

// ---------------------------------------------------------------------------
extern "C" void kernel_launch(void* const* d_in, const int* in_sizes, int n_in,
                              void* d_out, int out_size, void* d_ws, size_t ws_size,
                              hipStream_t stream) {
    const float* x = (const float*)d_in[0];
    const float* W1 = (const float*)d_in[1];
    const float* W2 = (const float*)d_in[2];
    const float* alpha = (const float*)d_in[3];
    float* out = (float*)d_out;

    // workspace layout (bytes, all 16B-aligned):
    // K f32 [B*T*N] | KW1 f32 [B*T*R] | QW2 f32 [B*T*R] | Abf u16 [B*T*T] | xbf u16 [B*C*N*T]
    char* ws = (char*)d_ws;
    float* K = (float*)ws;                       ws += (size_t)B_ * T_ * N_ * 4;
    float* KW1 = (float*)ws;                     ws += (size_t)B_ * T_ * R_ * 4;
    float* QW2 = (float*)ws;                     ws += (size_t)B_ * T_ * R_ * 4;
    unsigned short* Abf = (unsigned short*)ws;   ws += (size_t)B_ * T_ * T_ * 2;
    unsigned short* xbf = (unsigned short*)ws;
    size_t need = (size_t)(ws - (char*)d_ws) + (size_t)B_ * C_ * N_ * T_ * 2;
    const bool use_bf = (ws_size >= need);

    {
        int total = B_ * N_ * (T_ / 4);
        int blks = (total + 255) / 256;
        if (use_bf)
            k_reduce<1><<<blks, 256, 0, stream>>>(x, alpha, K, xbf);
        else
            k_reduce<0><<<blks, 256, 0, stream>>>(x, alpha, K, xbf);
    }
    {
        int total = B_ * T_ * 2 * R_;
        k_proj<<<(total + 255) / 256, 256, 0, stream>>>(K, W1, W2, KW1, QW2);
    }
    k_softmax<<<B_ * T_, 64, 0, stream>>>(KW1, QW2, Abf);
    {
        dim3 grid(M_ / 64, T_ / 96, B_);  // 307 x 3 x 16
        if (use_bf)
            k_out<1><<<grid, 256, 0, stream>>>(nullptr, xbf, Abf, out);
        else
            k_out<0><<<grid, 256, 0, stream>>>(x, nullptr, Abf, out);
    }
}